// Round 7
// baseline (422.597 us; speedup 1.0000x reference)
//
#include <hip/hip_runtime.h>
#include <math.h>

#define THRESH    0.5f
#define NEG_POSK  3
#define EPSf      1e-6f
#define CCLS      81
#define TILEA     64
#define CHUNKS    16

__device__ __forceinline__ float iou_xy(float ax0, float ay0, float ax1, float ay1,
                                        float bx0, float by0, float bx1, float by1) {
    float lx = fmaxf(ax0, bx0), ly = fmaxf(ay0, by0);
    float rx = fminf(ax1, bx1), ry = fminf(ay1, by1);
    float w = fmaxf(rx - lx, 0.f), h = fmaxf(ry - ly, 0.f);
    float inter = w * h;
    float aa = (ax1 - ax0) * (ay1 - ay0);
    float ab = (bx1 - bx0) * (by1 - by0);
    return inter / (aa + ab - inter);
}

// ---------- kernel 1: per-object best-anchor PARTIAL argmax (16 chunks) ----------
__global__ __launch_bounds__(256) void k_obj_part(const float* __restrict__ boxes,
                                                  const float* __restrict__ dboxes,
                                                  float* __restrict__ part_iou,
                                                  int* __restrict__ part_idx,
                                                  int N, int O) {
    int bo = blockIdx.x;                 // b*O + o  (block-uniform -> scalar loads)
    int c  = blockIdx.y;
    const float* bb = boxes + (size_t)bo * 4;
    float ax0 = bb[0], ay0 = bb[1], ax1 = bb[2], ay1 = bb[3];
    int chunk = (N + CHUNKS - 1) / CHUNKS;
    int n0 = c * chunk;
    int n1 = min(n0 + chunk, N);
    float best = -1.f; int bi = 0x7FFFFFFF;
    for (int n = n0 + threadIdx.x; n < n1; n += 256) {
        float4 d = ((const float4*)dboxes)[n];
        float dx0 = d.x - d.z * 0.5f, dy0 = d.y - d.w * 0.5f;
        float dx1 = d.x + d.z * 0.5f, dy1 = d.y + d.w * 0.5f;
        float iou = iou_xy(ax0, ay0, ax1, ay1, dx0, dy0, dx1, dy1);
        if (iou > best) { best = iou; bi = n; }   // ascending n + strict > = first max
    }
    #pragma unroll
    for (int dd = 1; dd < 64; dd <<= 1) {
        float v2 = __shfl_xor(best, dd); int i2 = __shfl_xor(bi, dd);
        if (v2 > best || (v2 == best && i2 < bi)) { best = v2; bi = i2; }
    }
    __shared__ float sv[4]; __shared__ int si[4];
    int w = threadIdx.x >> 6;
    if ((threadIdx.x & 63) == 0) { sv[w] = best; si[w] = bi; }
    __syncthreads();
    if (threadIdx.x == 0) {
        #pragma unroll
        for (int i = 1; i < 4; ++i)
            if (sv[i] > best || (sv[i] == best && si[i] < bi)) { best = sv[i]; bi = si[i]; }
        part_iou[(size_t)bo * CHUNKS + c] = best;
        part_idx[(size_t)bo * CHUNKS + c] = bi;
    }
}

// ---------- kernel 2: reduce the 16 partials per (b,o) ---------------------------
__global__ void k_obj_reduce(const float* __restrict__ part_iou,
                             const int* __restrict__ part_idx,
                             int* __restrict__ defbox_object, int BO) {
    int bo = blockIdx.x * blockDim.x + threadIdx.x;
    if (bo >= BO) return;
    float best = -1.f; int bi = 0x7FFFFFFF;
    #pragma unroll
    for (int c = 0; c < CHUNKS; ++c) {
        float v = part_iou[(size_t)bo * CHUNKS + c];
        int  i = part_idx[(size_t)bo * CHUNKS + c];
        if (v > best || (v == best && i < bi)) { best = v; bi = i; }
    }
    defbox_object[bo] = bi;
}

// ---------- kernel 3: register match + label + smooth-L1 (no cls access) ---------
template<int OT>
__global__ __launch_bounds__(256)
void k_match2(const float* __restrict__ locs_pred,
              const float* __restrict__ boxes,
              const int* __restrict__ labels,
              const float* __restrict__ dboxes,
              const int* __restrict__ dbo_g,
              int* __restrict__ t_label,
              int* __restrict__ n_pos,
              float* __restrict__ loc_sum,
              int N, int O_rt) {
    const int O = OT ? OT : O_rt;
    const int b = blockIdx.y;
    const float* __restrict__ bb = boxes + (size_t)b * O * 4;
    const int* __restrict__ lb   = labels + (size_t)b * O;
    const int* __restrict__ dbo  = dbo_g + (size_t)b * O;
    float ls = 0.f; int cnt = 0;
    int n = blockIdx.x * blockDim.x + threadIdx.x;
    if (n < N) {
        const size_t idx = (size_t)b * N + n;
        float4 d = ((const float4*)dboxes)[n];
        float dx0 = d.x - d.z * 0.5f, dy0 = d.y - d.w * 0.5f;
        float dx1 = d.x + d.z * 0.5f, dy1 = d.y + d.w * 0.5f;
        float best = -1.f; int sel = 0;
        #pragma unroll
        for (int o = 0; o < O; ++o) {
            float iou = iou_xy(bb[o*4], bb[o*4+1], bb[o*4+2], bb[o*4+3],
                               dx0, dy0, dx1, dy1);
            if (iou > best) { best = iou; sel = o; }   // first-max (JAX argmax axis=0)
        }
        bool forced = false;
        #pragma unroll
        for (int o = 0; o < O; ++o)
            if (dbo[o] == n) { sel = o; forced = true; }   // last-wins scatter
        float iou_eff = forced ? 1.0f : best;
        int lbl = (iou_eff < THRESH) ? 0 : lb[sel];
        t_label[idx] = lbl;
        if (lbl != 0) {
            cnt = 1;
            float bx0 = bb[sel*4], by0 = bb[sel*4+1], bx1 = bb[sel*4+2], by1 = bb[sel*4+3];
            float bcx = (bx0 + bx1) * 0.5f, bcy = (by0 + by1) * 0.5f;
            float bw = bx1 - bx0, bh = by1 - by0;
            float t0 = (bcx - d.x) / (d.z / 10.0f + EPSf);
            float t1 = (bcy - d.y) / (d.w / 10.0f + EPSf);
            float t2 = __logf(bw / d.z + EPSf) * 5.0f;
            float t3 = __logf(bh / d.w + EPSf) * 5.0f;
            float4 p = ((const float4*)locs_pred)[idx];
            float dd;
            dd = fabsf(p.x - t0); ls += (dd < 1.f) ? 0.5f*dd*dd : dd - 0.5f;
            dd = fabsf(p.y - t1); ls += (dd < 1.f) ? 0.5f*dd*dd : dd - 0.5f;
            dd = fabsf(p.z - t2); ls += (dd < 1.f) ? 0.5f*dd*dd : dd - 0.5f;
            dd = fabsf(p.w - t3); ls += (dd < 1.f) ? 0.5f*dd*dd : dd - 0.5f;
        }
    }
    #pragma unroll
    for (int dd = 1; dd < 64; dd <<= 1) {
        ls  += __shfl_xor(ls, dd);
        cnt += __shfl_xor(cnt, dd);
    }
    if ((threadIdx.x & 63) == 0 && cnt) {
        atomicAdd(&n_pos[b], cnt);
        atomicAdd(loc_sum, ls);
    }
}

// ---------- kernel 4: CE — coalesced stage+exp (probe-proven), 1-wave phase 2 ----
// Phase 1: 256 threads, 5-deep independent float4 loads + __expf + linear LDS
// (probe kA structure: ~10 TB/s equivalent). Phase 2: wave 0 only, one full row
// per thread, 81 unrolled ds_read_b32 (bank = 17t+c mod 32 -> 2 lanes/bank, free),
// dense coalesced t_label/vneg.
__global__ __launch_bounds__(256) void k_conf(const float* __restrict__ cls,
                                              const int* __restrict__ t_label,
                                              float* __restrict__ vneg,
                                              float* __restrict__ pos_conf,
                                              int B, int N) {
    __shared__ __align__(16) float sm[TILEA * CCLS];   // 20736 f32 = 20.7 KB
    int b = blockIdx.y;
    int a0 = blockIdx.x * TILEA;
    int valid = min(TILEA, N - a0);
    const float* g = cls + ((size_t)b * N + a0) * CCLS;  // 16B-aligned (see notes)
    const float4* g4 = (const float4*)g;
    float4* sm4 = (float4*)sm;
    int tid = threadIdx.x;
    if (valid == TILEA) {
        float4 r0 = g4[tid];
        float4 r1 = g4[tid + 256];
        float4 r2 = g4[tid + 512];
        float4 r3 = g4[tid + 768];
        float4 r4 = g4[tid + 1024];
        float4 r5;
        if (tid < 16) r5 = g4[tid + 1280];                // 1296 = 5*256 + 16
        r0.x=__expf(r0.x); r0.y=__expf(r0.y); r0.z=__expf(r0.z); r0.w=__expf(r0.w);
        r1.x=__expf(r1.x); r1.y=__expf(r1.y); r1.z=__expf(r1.z); r1.w=__expf(r1.w);
        r2.x=__expf(r2.x); r2.y=__expf(r2.y); r2.z=__expf(r2.z); r2.w=__expf(r2.w);
        r3.x=__expf(r3.x); r3.y=__expf(r3.y); r3.z=__expf(r3.z); r3.w=__expf(r3.w);
        r4.x=__expf(r4.x); r4.y=__expf(r4.y); r4.z=__expf(r4.z); r4.w=__expf(r4.w);
        sm4[tid]        = r0;
        sm4[tid + 256]  = r1;
        sm4[tid + 512]  = r2;
        sm4[tid + 768]  = r3;
        sm4[tid + 1024] = r4;
        if (tid < 16) {
            r5.x=__expf(r5.x); r5.y=__expf(r5.y); r5.z=__expf(r5.z); r5.w=__expf(r5.w);
            sm4[tid + 1280] = r5;
        }
    } else {
        int len = valid * CCLS, nvec = len >> 2;
        for (int iv = tid; iv < nvec; iv += 256) {
            float4 v = g4[iv];
            v.x=__expf(v.x); v.y=__expf(v.y); v.z=__expf(v.z); v.w=__expf(v.w);
            sm4[iv] = v;
        }
        for (int i = (nvec << 2) + tid; i < len; i += 256) sm[i] = __expf(g[i]);
    }
    __syncthreads();

    if (tid >= TILEA) return;                   // waves 1-3 done
    float pc = 0.f;
    if (tid < valid) {
        const float* row = &sm[tid * CCLS];
        float s = 0.f;
        #pragma unroll
        for (int c = 0; c < CCLS; ++c) s += row[c];    // 81 ds_read_b32, batched
        size_t idx = (size_t)b * N + a0 + tid;
        int lbl = t_label[idx];                        // 64 consecutive ints
        float conf = __logf(s) - __logf(row[lbl]);     // x[lbl] = log(exp-val)
        bool pos = (lbl != 0);
        vneg[idx] = pos ? 0.f : conf;                  // 256 B coalesced store
        pc = pos ? conf : 0.f;
    }
    #pragma unroll
    for (int dd = 1; dd < 64; dd <<= 1) pc += __shfl_xor(pc, dd);
    if (tid == 0 && pc != 0.f) atomicAdd(pos_conf, pc);
}

// ---------- kernel 5: exact top-k sum of negatives per batch ---------------------
__device__ __forceinline__ void hist_add_agg(int* hist, unsigned bin, bool valid) {
    int lane = threadIdx.x & 63;
    unsigned long long remaining = __ballot(valid);
    while (remaining) {
        int leader = __ffsll(remaining) - 1;
        unsigned lbin = __shfl(bin, leader);
        unsigned long long match = __ballot(valid && bin == lbin);
        if (lane == leader) atomicAdd(&hist[lbin], (int)__popcll(match));
        remaining &= ~match;
    }
}

__device__ void wave_select(const int* hist, int nbins, int k, int* out_bin, int* out_k) {
    int lane = threadIdx.x & 63;
    int cum = 0;
    for (int c = nbins / 64 - 1; c >= 0; --c) {
        int val = hist[c * 64 + lane];
        int s = val;
        for (int d = 1; d < 64; d <<= 1) {
            int t = __shfl_down(s, d);
            if (lane + d < 64) s += t;
        }
        int total = __shfl(s, 0);
        if (cum + total >= k) {
            unsigned long long mask = __ballot(cum + s >= k);
            int bl = 63 - __builtin_clzll(mask);
            int sB = __shfl(s, bl);
            int vB = __shfl(val, bl);
            if (lane == 0) {
                *out_bin = c * 64 + bl;
                *out_k = k - (cum + sB - vB);
            }
            return;
        }
        cum += total;
    }
    if (lane == 0) { *out_bin = 0; *out_k = 1; }
}

__global__ __launch_bounds__(1024) void k_select(const float* __restrict__ vneg,
                                                 const int* __restrict__ n_pos,
                                                 float* __restrict__ hard_sum,
                                                 int B, int N) {
    int b = blockIdx.x;
    const float* v = vneg + (size_t)b * N;
    __shared__ int hist[2048];
    __shared__ int bcast_bin, bcast_k;
    __shared__ float swv[16];
    __shared__ int swc[16];
    int np = n_pos[b];
    long long kk = (long long)NEG_POSK * np;
    if (kk > N) kk = N;
    int k = (int)kk;
    if (k <= 0) return;
    int tid = threadIdx.x;
    int Npad = ((N + 1023) / 1024) * 1024;

    for (int i = tid; i < 2048; i += 1024) hist[i] = 0;
    __syncthreads();
    for (int base = 0; base < Npad; base += 1024) {
        int n = base + tid;
        bool valid = n < N;
        unsigned u = valid ? __float_as_uint(v[n]) : 0u;
        hist_add_agg(hist, u >> 20, valid);
    }
    __syncthreads();
    if (tid < 64) wave_select(hist, 2048, k, &bcast_bin, &bcast_k);
    __syncthreads();
    int B1 = bcast_bin, k2 = bcast_k;

    for (int i = tid; i < 2048; i += 1024) hist[i] = 0;
    __syncthreads();
    for (int base = 0; base < Npad; base += 1024) {
        int n = base + tid;
        bool valid = n < N;
        unsigned u = valid ? __float_as_uint(v[n]) : 0u;
        hist_add_agg(hist, (u >> 9) & 0x7FF, valid && (int)(u >> 20) == B1);
    }
    __syncthreads();
    if (tid < 64) wave_select(hist, 2048, k2, &bcast_bin, &bcast_k);
    __syncthreads();
    int B2 = bcast_bin, k3 = bcast_k;
    unsigned pre = ((unsigned)B1 << 11) | (unsigned)B2;

    for (int i = tid; i < 512; i += 1024) hist[i] = 0;
    __syncthreads();
    for (int base = 0; base < Npad; base += 1024) {
        int n = base + tid;
        bool valid = n < N;
        unsigned u = valid ? __float_as_uint(v[n]) : 0u;
        hist_add_agg(hist, u & 0x1FF, valid && (u >> 9) == pre);
    }
    __syncthreads();
    if (tid < 64) wave_select(hist, 512, k3, &bcast_bin, &bcast_k);
    __syncthreads();
    unsigned tau_bits = (pre << 9) | (unsigned)bcast_bin;
    float tau = __uint_as_float(tau_bits);

    float ssum = 0.f; int scnt = 0;
    for (int n = tid; n < N; n += 1024) {
        float x = v[n];
        if (x > tau) { ssum += x; scnt++; }
    }
    for (int d = 1; d < 64; d <<= 1) {
        ssum += __shfl_xor(ssum, d);
        scnt += __shfl_xor(scnt, d);
    }
    int w = tid >> 6;
    if ((tid & 63) == 0) { swv[w] = ssum; swc[w] = scnt; }
    __syncthreads();
    if (tid == 0) {
        float S = 0.f; int Ct = 0;
        for (int i = 0; i < 16; ++i) { S += swv[i]; Ct += swc[i]; }
        float hb = S + (float)(k - Ct) * tau;
        atomicAdd(hard_sum, hb);
    }
}

// ---------- kernel 6: finalize ---------------------------------------------------
__global__ void k_final(const int* __restrict__ n_pos,
                        const float* __restrict__ loc_sum,
                        const float* __restrict__ pos_conf,
                        const float* __restrict__ hard_sum,
                        float* __restrict__ out, int B) {
    if (threadIdx.x == 0 && blockIdx.x == 0) {
        int tot = 0;
        for (int b = 0; b < B; ++b) tot += n_pos[b];
        float np = (float)tot;
        float loc = *loc_sum / (np * 4.0f);
        float conf = (*hard_sum + *pos_conf) / np;
        out[0] = 0.5f * loc + conf;
    }
}

extern "C" void kernel_launch(void* const* d_in, const int* in_sizes, int n_in,
                              void* d_out, int out_size, void* d_ws, size_t ws_size,
                              hipStream_t stream) {
    const float* locs_pred = (const float*)d_in[0];
    const float* cls_pred  = (const float*)d_in[1];
    const float* boxes     = (const float*)d_in[2];
    const int*   labels    = (const int*)d_in[3];
    const float* dboxes    = (const float*)d_in[4];

    int N = in_sizes[4] / 4;
    int B = in_sizes[0] / (4 * N);
    int O = in_sizes[3] / B;
    int BO = B * O;

    size_t BN = (size_t)B * N;
    char* ws = (char*)d_ws;
    int*   n_pos    = (int*)ws;                         // B ints
    float* loc_sum  = (float*)(ws + 128);
    float* pos_conf = (float*)(ws + 132);
    float* hard_sum = (float*)(ws + 136);
    int*   t_label  = (int*)(ws + 256);                 // BN i32
    float* vneg     = (float*)(ws + 256 + BN * 4);      // BN f32
    int*   defbox_object = (int*)(ws + 256 + BN * 8);   // BO i32
    float* part_iou = (float*)(ws + 256 + BN * 8 + (size_t)BO * 4);
    int*   part_idx = (int*)(ws + 256 + BN * 8 + (size_t)BO * 4 + (size_t)BO * CHUNKS * 4);

    hipMemsetAsync(ws, 0, 256, stream);

    dim3 gop(BO, CHUNKS);
    k_obj_part<<<gop, 256, 0, stream>>>(boxes, dboxes, part_iou, part_idx, N, O);
    k_obj_reduce<<<(BO + 255) / 256, 256, 0, stream>>>(part_iou, part_idx,
                                                       defbox_object, BO);
    dim3 gm((N + 255) / 256, B);
    if (O == 16)
        k_match2<16><<<gm, 256, 0, stream>>>(locs_pred, boxes, labels, dboxes,
                                             defbox_object, t_label, n_pos, loc_sum,
                                             N, O);
    else
        k_match2<0><<<gm, 256, 0, stream>>>(locs_pred, boxes, labels, dboxes,
                                            defbox_object, t_label, n_pos, loc_sum,
                                            N, O);
    dim3 gc((N + TILEA - 1) / TILEA, B);
    k_conf<<<gc, 256, 0, stream>>>(cls_pred, t_label, vneg, pos_conf, B, N);
    k_select<<<B, 1024, 0, stream>>>(vneg, n_pos, hard_sum, B, N);
    k_final<<<1, 1, 0, stream>>>(n_pos, loc_sum, pos_conf, hard_sum, (float*)d_out, B);
}